// Round 1
// baseline (1804.225 us; speedup 1.0000x reference)
//
#include <hip/hip_runtime.h>
#include <cstdint>

#define DIN 256
#define DH 128
#define DOUT 32

// ---------------- degree / normalization ----------------

__global__ void k_init_deg(int* deg, int n) {
    int i = blockIdx.x * blockDim.x + threadIdx.x;
    if (i < n) deg[i] = 1;  // self-loop contributes 1
}

__global__ void k_count(const int* __restrict__ dst, int* __restrict__ deg, int e) {
    int i = blockIdx.x * blockDim.x + threadIdx.x;
    if (i < e) atomicAdd(&deg[dst[i]], 1);
}

__global__ void k_dis(float* dis, int n) {
    int i = blockIdx.x * blockDim.x + threadIdx.x;
    if (i < n) {
        int d = ((const int*)dis)[i];
        dis[i] = rsqrtf((float)d);
    }
}

// ---------------- GEMM1: h = x @ W1 ; agg = h * dis^2 (self-loop term) ----------------
// 64 rows x 128 cols per block, 256 threads, BK=32, fp32.

__global__ __launch_bounds__(256) void k_gemm1(
    const float* __restrict__ x, const float* __restrict__ W1,
    const float* __restrict__ dis, float* __restrict__ h,
    float* __restrict__ agg, int n) {
    __shared__ float xs[64][36];      // +4 pad keeps 16B alignment, breaks bank conflicts
    __shared__ float wsh[32][DH];
    int tid = threadIdx.x;
    int row0 = blockIdx.x * 64;
    int tr = tid >> 5;   // 0..7  (8 rows each)
    int tc = tid & 31;   // 0..31 (4 cols each)
    float acc[8][4] = {};

    for (int kc = 0; kc < DIN; kc += 32) {
        {   // stage x tile: 64 rows x 32 k
            int r = tid >> 2;
            int p = tid & 3;
            int rr = row0 + r; if (rr >= n) rr = n - 1;
            const float4* xr = (const float4*)(x + (size_t)rr * DIN + kc);
            float4 v0 = xr[p];
            float4 v1 = xr[p + 4];
            *(float4*)&xs[r][p * 4] = v0;
            *(float4*)&xs[r][16 + p * 4] = v1;
        }
        {   // stage W1 chunk: 32 x 128 contiguous
            const float4* wp = (const float4*)(W1 + (size_t)kc * DH);
            float4* wl = (float4*)&wsh[0][0];
            #pragma unroll
            for (int j = 0; j < 4; ++j) wl[tid + j * 256] = wp[tid + j * 256];
        }
        __syncthreads();
        #pragma unroll
        for (int k4 = 0; k4 < 8; ++k4) {
            float4 b0 = *(const float4*)&wsh[k4 * 4 + 0][tc * 4];
            float4 b1 = *(const float4*)&wsh[k4 * 4 + 1][tc * 4];
            float4 b2 = *(const float4*)&wsh[k4 * 4 + 2][tc * 4];
            float4 b3 = *(const float4*)&wsh[k4 * 4 + 3][tc * 4];
            #pragma unroll
            for (int i = 0; i < 8; ++i) {
                float4 a = *(const float4*)&xs[tr * 8 + i][k4 * 4];
                acc[i][0] += a.x * b0.x + a.y * b1.x + a.z * b2.x + a.w * b3.x;
                acc[i][1] += a.x * b0.y + a.y * b1.y + a.z * b2.y + a.w * b3.y;
                acc[i][2] += a.x * b0.z + a.y * b1.z + a.z * b2.z + a.w * b3.z;
                acc[i][3] += a.x * b0.w + a.y * b1.w + a.z * b2.w + a.w * b3.w;
            }
        }
        __syncthreads();
    }

    #pragma unroll
    for (int i = 0; i < 8; ++i) {
        int r = row0 + tr * 8 + i;
        if (r < n) {
            float dv = dis[r];
            float co = dv * dv;
            float4 v = make_float4(acc[i][0], acc[i][1], acc[i][2], acc[i][3]);
            *(float4*)&h[(size_t)r * DH + tc * 4] = v;
            float4 va = make_float4(v.x * co, v.y * co, v.z * co, v.w * co);
            *(float4*)&agg[(size_t)r * DH + tc * 4] = va;
        }
    }
}

// ---------------- scatter layer 1: agg[dst] += h[src] * dis[src]*dis[dst] ----------------
// one wave per edge; lane handles 2 floats (float2 gather, 2 scalar atomics)

__global__ __launch_bounds__(256) void k_scatter1(
    const float* __restrict__ h, const float* __restrict__ dis,
    const int* __restrict__ src, const int* __restrict__ dst,
    float* __restrict__ agg, int e) {
    int eid = blockIdx.x * 4 + (threadIdx.x >> 6);
    if (eid >= e) return;
    int lane = threadIdx.x & 63;
    int s = src[eid], d = dst[eid];
    float coef = dis[s] * dis[d];
    float2 v = *(const float2*)(h + (size_t)s * DH + lane * 2);
    float* a = agg + (size_t)d * DH + lane * 2;
    atomicAdd(a, v.x * coef);
    atomicAdd(a + 1, v.y * coef);
}

// ---------------- h1 = relu(agg + b1) (writes over h buffer) ----------------

__global__ void k_relu_bias(const float* __restrict__ agg, const float* __restrict__ b1,
                            float* __restrict__ h1, long long n4) {
    long long i = (long long)blockIdx.x * blockDim.x + threadIdx.x;
    if (i >= n4) return;
    int c4 = (int)(i & (DH / 4 - 1));
    float4 v = ((const float4*)agg)[i];
    float4 b = ((const float4*)b1)[c4];
    v.x = fmaxf(v.x + b.x, 0.f);
    v.y = fmaxf(v.y + b.y, 0.f);
    v.z = fmaxf(v.z + b.z, 0.f);
    v.w = fmaxf(v.w + b.w, 0.f);
    ((float4*)h1)[i] = v;
}

// ---------------- GEMM2: h2 = h1 @ W2 ; out = h2 * dis^2 ----------------
// thread computes 4 cols of one row; 8 threads per row.

__global__ __launch_bounds__(256) void k_gemm2(
    const float* __restrict__ h1, const float* __restrict__ W2,
    const float* __restrict__ dis, float* __restrict__ h2,
    float* __restrict__ out, int n) {
    int t = blockIdx.x * blockDim.x + threadIdx.x;
    int row = t >> 3;
    int cg = t & 7;
    if (row >= n) return;
    const float4* hr = (const float4*)(h1 + (size_t)row * DH);
    const float4* w4 = (const float4*)W2;   // [128][32] -> float4 idx k*8 + cg
    float4 acc = make_float4(0.f, 0.f, 0.f, 0.f);
    #pragma unroll 8
    for (int k4 = 0; k4 < DH / 4; ++k4) {
        float4 a = hr[k4];
        float4 w0 = w4[(k4 * 4 + 0) * 8 + cg];
        float4 w1 = w4[(k4 * 4 + 1) * 8 + cg];
        float4 w2 = w4[(k4 * 4 + 2) * 8 + cg];
        float4 w3 = w4[(k4 * 4 + 3) * 8 + cg];
        acc.x += a.x * w0.x + a.y * w1.x + a.z * w2.x + a.w * w3.x;
        acc.y += a.x * w0.y + a.y * w1.y + a.z * w2.y + a.w * w3.y;
        acc.z += a.x * w0.z + a.y * w1.z + a.z * w2.z + a.w * w3.z;
        acc.w += a.x * w0.w + a.y * w1.w + a.z * w2.w + a.w * w3.w;
    }
    float dv = dis[row];
    float co = dv * dv;
    ((float4*)h2)[(size_t)row * 8 + cg] = acc;
    float4 vo = make_float4(acc.x * co, acc.y * co, acc.z * co, acc.w * co);
    ((float4*)out)[(size_t)row * 8 + cg] = vo;
}

// ---------------- scatter layer 2: out[dst] += h2[src] * coef ----------------
// thread per (edge, col)

__global__ __launch_bounds__(256) void k_scatter2(
    const float* __restrict__ h2, const float* __restrict__ dis,
    const int* __restrict__ src, const int* __restrict__ dst,
    float* __restrict__ out, int e) {
    long long t = (long long)blockIdx.x * blockDim.x + threadIdx.x;
    int eid = (int)(t >> 5);
    if (eid >= e) return;
    int c = (int)(t & 31);
    int s = src[eid], d = dst[eid];
    float coef = dis[s] * dis[d];
    atomicAdd(&out[(size_t)d * DOUT + c], h2[(size_t)s * DOUT + c] * coef);
}

// ---------------- log_softmax(out + b2) in-place, 32-lane groups ----------------

__global__ __launch_bounds__(256) void k_lsm(float* __restrict__ out,
                                             const float* __restrict__ b2, int n) {
    long long t = (long long)blockIdx.x * blockDim.x + threadIdx.x;
    int r = (int)(t >> 5);
    if (r >= n) return;
    int c = (int)(t & 31);
    float v = out[(size_t)r * DOUT + c] + b2[c];
    float m = v;
    #pragma unroll
    for (int off = 16; off > 0; off >>= 1) m = fmaxf(m, __shfl_xor(m, off));
    float ev = __expf(v - m);
    float s = ev;
    #pragma unroll
    for (int off = 16; off > 0; off >>= 1) s += __shfl_xor(s, off);
    out[(size_t)r * DOUT + c] = v - m - __logf(s);
}

extern "C" void kernel_launch(void* const* d_in, const int* in_sizes, int n_in,
                              void* d_out, int out_size, void* d_ws, size_t ws_size,
                              hipStream_t stream) {
    const float* x  = (const float*)d_in[0];
    const int*   ei = (const int*)d_in[1];
    const float* W1 = (const float*)d_in[2];
    const float* b1 = (const float*)d_in[3];
    const float* W2 = (const float*)d_in[4];
    const float* b2 = (const float*)d_in[5];
    int n = in_sizes[0] / DIN;
    int e = in_sizes[1] / 2;
    const int* src = ei;
    const int* dst = ei + e;
    float* out = (float*)d_out;

    // workspace layout: dis[n] | h[n*128] | agg[n*128] | h2[n*32]  (~116 MB)
    float* ws_f = (float*)d_ws;
    float* dis = ws_f;
    float* h   = dis + n;
    float* agg = h + (size_t)n * DH;
    float* h2  = agg + (size_t)n * DH;

    k_init_deg<<<(n + 255) / 256, 256, 0, stream>>>((int*)dis, n);
    k_count<<<(e + 255) / 256, 256, 0, stream>>>(dst, (int*)dis, e);
    k_dis<<<(n + 255) / 256, 256, 0, stream>>>(dis, n);
    k_gemm1<<<(n + 63) / 64, 256, 0, stream>>>(x, W1, dis, h, agg, n);
    k_scatter1<<<(e + 3) / 4, 256, 0, stream>>>(h, dis, src, dst, agg, e);
    long long n4 = (long long)n * DH / 4;
    k_relu_bias<<<(int)((n4 + 255) / 256), 256, 0, stream>>>(agg, b1, h, n4);
    k_gemm2<<<(n * 8 + 255) / 256, 256, 0, stream>>>(h, W2, dis, h2, out, n);
    long long t2 = (long long)e * 32;
    k_scatter2<<<(int)((t2 + 255) / 256), 256, 0, stream>>>(h2, dis, src, dst, out, e);
    long long t3 = (long long)n * 32;
    k_lsm<<<(int)((t3 + 255) / 256), 256, 0, stream>>>(out, b2, n);
}

// Round 2
// 603.123 us; speedup vs baseline: 2.9915x; 2.9915x over previous
//
#include <hip/hip_runtime.h>
#include <cstdint>

#define DIN 256
#define DH 128
#define DOUT 32

// ---------------- degree / normalization ----------------

__global__ void k_init_deg(int* deg, int n) {
    int i = blockIdx.x * blockDim.x + threadIdx.x;
    if (i < n) deg[i] = 1;  // self-loop contributes 1
}

__global__ void k_count(const int* __restrict__ dst, int* __restrict__ deg, int e) {
    int i = blockIdx.x * blockDim.x + threadIdx.x;
    if (i < e) atomicAdd(&deg[dst[i]], 1);
}

__global__ void k_dis(const int* __restrict__ deg, float* __restrict__ dis, int n) {
    int i = blockIdx.x * blockDim.x + threadIdx.x;
    if (i < n) dis[i] = rsqrtf((float)deg[i]);
}

// ---------------- CSR build: exclusive scan of (deg-1), then bucket fill ----------------

__global__ __launch_bounds__(256) void k_scan1(const int* __restrict__ deg,
                                               int* __restrict__ offs,
                                               int* __restrict__ bsum, int n) {
    __shared__ int sh[256];
    int base = blockIdx.x * 1024;
    int t = threadIdx.x;
    int v[4];
    int sum = 0;
    #pragma unroll
    for (int j = 0; j < 4; ++j) {
        int i = base + t * 4 + j;
        int d = (i < n) ? (deg[i] - 1) : 0;  // CSR holds only real edges
        v[j] = sum;
        sum += d;
    }
    sh[t] = sum;
    __syncthreads();
    #pragma unroll
    for (int off = 1; off < 256; off <<= 1) {
        int x = (t >= off) ? sh[t - off] : 0;
        __syncthreads();
        if (t >= off) sh[t] += x;
        __syncthreads();
    }
    int excl = (t == 0) ? 0 : sh[t - 1];
    if (t == 255) bsum[blockIdx.x] = sh[255];
    #pragma unroll
    for (int j = 0; j < 4; ++j) {
        int i = base + t * 4 + j;
        if (i < n) offs[i] = excl + v[j];
    }
}

__global__ __launch_bounds__(256) void k_scan2(int* __restrict__ bsum, int nb) {
    __shared__ int sh[256];
    int t = threadIdx.x;
    sh[t] = (t < nb) ? bsum[t] : 0;
    __syncthreads();
    #pragma unroll
    for (int off = 1; off < 256; off <<= 1) {
        int x = (t >= off) ? sh[t - off] : 0;
        __syncthreads();
        if (t >= off) sh[t] += x;
        __syncthreads();
    }
    int excl = (t == 0) ? 0 : sh[t - 1];
    if (t < nb) bsum[t] = excl;
}

__global__ void k_scan3(int* __restrict__ offs, int* __restrict__ cursor,
                        const int* __restrict__ bsum, int n) {
    int i = blockIdx.x * blockDim.x + threadIdx.x;
    if (i < n) {
        int o = offs[i] + bsum[i >> 10];
        offs[i] = o;
        cursor[i] = o;
    }
}

__global__ void k_fill(const int* __restrict__ src, const int* __restrict__ dst,
                       const float* __restrict__ dis, int* __restrict__ cursor,
                       int* __restrict__ adj, float* __restrict__ acoef, int e) {
    int i = blockIdx.x * blockDim.x + threadIdx.x;
    if (i >= e) return;
    int s = src[i], d = dst[i];
    int pos = atomicAdd(&cursor[d], 1);
    adj[pos] = s;
    acoef[pos] = dis[s] * dis[d];
}

// ---------------- GEMM1: h = x @ W1 (fp32, 64x128 tile) ----------------

__global__ __launch_bounds__(256) void k_gemm1(
    const float* __restrict__ x, const float* __restrict__ W1,
    float* __restrict__ h, int n) {
    __shared__ float xs[64][36];
    __shared__ float wsh[32][DH];
    int tid = threadIdx.x;
    int row0 = blockIdx.x * 64;
    int tr = tid >> 5;
    int tc = tid & 31;
    float acc[8][4] = {};

    for (int kc = 0; kc < DIN; kc += 32) {
        {
            int r = tid >> 2;
            int p = tid & 3;
            int rr = row0 + r; if (rr >= n) rr = n - 1;
            const float4* xr = (const float4*)(x + (size_t)rr * DIN + kc);
            float4 v0 = xr[p];
            float4 v1 = xr[p + 4];
            *(float4*)&xs[r][p * 4] = v0;
            *(float4*)&xs[r][16 + p * 4] = v1;
        }
        {
            const float4* wp = (const float4*)(W1 + (size_t)kc * DH);
            float4* wl = (float4*)&wsh[0][0];
            #pragma unroll
            for (int j = 0; j < 4; ++j) wl[tid + j * 256] = wp[tid + j * 256];
        }
        __syncthreads();
        #pragma unroll
        for (int k4 = 0; k4 < 8; ++k4) {
            float4 b0 = *(const float4*)&wsh[k4 * 4 + 0][tc * 4];
            float4 b1 = *(const float4*)&wsh[k4 * 4 + 1][tc * 4];
            float4 b2 = *(const float4*)&wsh[k4 * 4 + 2][tc * 4];
            float4 b3 = *(const float4*)&wsh[k4 * 4 + 3][tc * 4];
            #pragma unroll
            for (int i = 0; i < 8; ++i) {
                float4 a = *(const float4*)&xs[tr * 8 + i][k4 * 4];
                acc[i][0] += a.x * b0.x + a.y * b1.x + a.z * b2.x + a.w * b3.x;
                acc[i][1] += a.x * b0.y + a.y * b1.y + a.z * b2.y + a.w * b3.y;
                acc[i][2] += a.x * b0.z + a.y * b1.z + a.z * b2.z + a.w * b3.z;
                acc[i][3] += a.x * b0.w + a.y * b1.w + a.z * b2.w + a.w * b3.w;
            }
        }
        __syncthreads();
    }

    #pragma unroll
    for (int i = 0; i < 8; ++i) {
        int r = row0 + tr * 8 + i;
        if (r < n) {
            float4 v = make_float4(acc[i][0], acc[i][1], acc[i][2], acc[i][3]);
            *(float4*)&h[(size_t)r * DH + tc * 4] = v;
        }
    }
}

// ---------------- agg1 (fused): h1[i] = relu( h[i]*dis_i^2 + sum_nb h[s]*coef + b1 ) ----
// one 64-lane wave per node; lane owns 2 columns.

__global__ __launch_bounds__(256) void k_agg1(
    const float* __restrict__ h, const float* __restrict__ dis,
    const int* __restrict__ offs, const int* __restrict__ deg,
    const int* __restrict__ adj, const float* __restrict__ acoef,
    const float* __restrict__ b1, float* __restrict__ h1, int n) {
    int node = blockIdx.x * 4 + (threadIdx.x >> 6);
    if (node >= n) return;
    int lane = threadIdx.x & 63;
    float dv = dis[node];
    float self = dv * dv;
    float2 acc = *(const float2*)(h + (size_t)node * DH + lane * 2);
    acc.x *= self; acc.y *= self;

    int off = offs[node];
    int cnt = deg[node] - 1;
    int k = 0;
    for (; k + 1 < cnt; k += 2) {
        int s0 = adj[off + k], s1 = adj[off + k + 1];
        float c0 = acoef[off + k], c1 = acoef[off + k + 1];
        float2 v0 = *(const float2*)(h + (size_t)s0 * DH + lane * 2);
        float2 v1 = *(const float2*)(h + (size_t)s1 * DH + lane * 2);
        acc.x += v0.x * c0 + v1.x * c1;
        acc.y += v0.y * c0 + v1.y * c1;
    }
    if (k < cnt) {
        int s0 = adj[off + k];
        float c0 = acoef[off + k];
        float2 v0 = *(const float2*)(h + (size_t)s0 * DH + lane * 2);
        acc.x += v0.x * c0;
        acc.y += v0.y * c0;
    }
    float2 b = *(const float2*)(b1 + lane * 2);
    acc.x = fmaxf(acc.x + b.x, 0.f);
    acc.y = fmaxf(acc.y + b.y, 0.f);
    *(float2*)(h1 + (size_t)node * DH + lane * 2) = acc;
}

// ---------------- GEMM2: h2 = h1 @ W2 ----------------

__global__ __launch_bounds__(256) void k_gemm2(
    const float* __restrict__ h1, const float* __restrict__ W2,
    float* __restrict__ h2, int n) {
    int t = blockIdx.x * blockDim.x + threadIdx.x;
    int row = t >> 3;
    int cg = t & 7;
    if (row >= n) return;
    const float4* hr = (const float4*)(h1 + (size_t)row * DH);
    const float4* w4 = (const float4*)W2;
    float4 acc = make_float4(0.f, 0.f, 0.f, 0.f);
    #pragma unroll 8
    for (int k4 = 0; k4 < DH / 4; ++k4) {
        float4 a = hr[k4];
        float4 w0 = w4[(k4 * 4 + 0) * 8 + cg];
        float4 w1 = w4[(k4 * 4 + 1) * 8 + cg];
        float4 w2 = w4[(k4 * 4 + 2) * 8 + cg];
        float4 w3 = w4[(k4 * 4 + 3) * 8 + cg];
        acc.x += a.x * w0.x + a.y * w1.x + a.z * w2.x + a.w * w3.x;
        acc.y += a.x * w0.y + a.y * w1.y + a.z * w2.y + a.w * w3.y;
        acc.z += a.x * w0.z + a.y * w1.z + a.z * w2.z + a.w * w3.z;
        acc.w += a.x * w0.w + a.y * w1.w + a.z * w2.w + a.w * w3.w;
    }
    ((float4*)h2)[(size_t)row * 8 + cg] = acc;
}

// ---------------- agg2 + bias + log_softmax fused ----------------
// 32 threads per node (8 nodes per block); lane owns 1 column.

__global__ __launch_bounds__(256) void k_agg2_lsm(
    const float* __restrict__ h2, const float* __restrict__ dis,
    const int* __restrict__ offs, const int* __restrict__ deg,
    const int* __restrict__ adj, const float* __restrict__ acoef,
    const float* __restrict__ b2, float* __restrict__ out, int n) {
    int node = blockIdx.x * 8 + (threadIdx.x >> 5);
    if (node >= n) return;
    int c = threadIdx.x & 31;
    float dv = dis[node];
    float acc = h2[(size_t)node * DOUT + c] * dv * dv;

    int off = offs[node];
    int cnt = deg[node] - 1;
    int k = 0;
    for (; k + 1 < cnt; k += 2) {
        int s0 = adj[off + k], s1 = adj[off + k + 1];
        float c0 = acoef[off + k], c1 = acoef[off + k + 1];
        acc += h2[(size_t)s0 * DOUT + c] * c0 + h2[(size_t)s1 * DOUT + c] * c1;
    }
    if (k < cnt) {
        acc += h2[(size_t)adj[off + k] * DOUT + c] * acoef[off + k];
    }
    float v = acc + b2[c];
    float m = v;
    #pragma unroll
    for (int o = 16; o > 0; o >>= 1) m = fmaxf(m, __shfl_xor(m, o));
    float ev = __expf(v - m);
    float s = ev;
    #pragma unroll
    for (int o = 16; o > 0; o >>= 1) s += __shfl_xor(s, o);
    out[(size_t)node * DOUT + c] = v - m - __logf(s);
}

extern "C" void kernel_launch(void* const* d_in, const int* in_sizes, int n_in,
                              void* d_out, int out_size, void* d_ws, size_t ws_size,
                              hipStream_t stream) {
    const float* x  = (const float*)d_in[0];
    const int*   ei = (const int*)d_in[1];
    const float* W1 = (const float*)d_in[2];
    const float* b1 = (const float*)d_in[3];
    const float* W2 = (const float*)d_in[4];
    const float* b2 = (const float*)d_in[5];
    int n = in_sizes[0] / DIN;
    int e = in_sizes[1] / 2;
    const int* src = ei;
    const int* dst = ei + e;
    float* out = (float*)d_out;

    // workspace layout (bytes):
    // deg[n] | offs[n] | cursor[n] | bsum[256] | dis[n] | adj[e] | acoef[e] | h[n*128] | h1[n*128]
    // h2 aliases h (dead after agg1).   total ~ 117 MB
    char* p = (char*)d_ws;
    int*   deg    = (int*)p;          p += (size_t)n * 4;
    int*   offs   = (int*)p;          p += (size_t)n * 4;
    int*   cursor = (int*)p;          p += (size_t)n * 4;
    int*   bsum   = (int*)p;          p += 1024;
    float* dis    = (float*)p;        p += (size_t)n * 4;
    int*   adj    = (int*)p;          p += (size_t)e * 4;
    float* acoef  = (float*)p;        p += (size_t)e * 4;
    float* h      = (float*)p;        p += (size_t)n * DH * 4;
    float* h1     = (float*)p;
    float* h2     = h;   // h dead after k_agg1

    int nb = (n + 1023) / 1024;

    k_init_deg<<<(n + 255) / 256, 256, 0, stream>>>(deg, n);
    k_count<<<(e + 255) / 256, 256, 0, stream>>>(dst, deg, e);
    k_dis<<<(n + 255) / 256, 256, 0, stream>>>(deg, dis, n);
    k_scan1<<<nb, 256, 0, stream>>>(deg, offs, bsum, n);
    k_scan2<<<1, 256, 0, stream>>>(bsum, nb);
    k_scan3<<<(n + 255) / 256, 256, 0, stream>>>(offs, cursor, bsum, n);
    k_fill<<<(e + 255) / 256, 256, 0, stream>>>(src, dst, dis, cursor, adj, acoef, e);

    k_gemm1<<<(n + 63) / 64, 256, 0, stream>>>(x, W1, h, n);
    k_agg1<<<(n + 3) / 4, 256, 0, stream>>>(h, dis, offs, deg, adj, acoef, b1, h1, n);
    k_gemm2<<<(n * 8 + 255) / 256, 256, 0, stream>>>(h1, W2, h2, n);
    k_agg2_lsm<<<(n + 7) / 8, 256, 0, stream>>>(h2, dis, offs, deg, adj, acoef, b2, out, n);
}

// Round 3
// 470.166 us; speedup vs baseline: 3.8374x; 1.2828x over previous
//
#include <hip/hip_runtime.h>
#include <cstdint>

#define DIN 256
#define DH 128
#define DOUT 32

typedef short s16x8 __attribute__((ext_vector_type(8)));
typedef float f32x4 __attribute__((ext_vector_type(4)));

__device__ inline ushort f2bf(float f) {
    uint u = __float_as_uint(f);
    u += 0x7fff + ((u >> 16) & 1);   // round-to-nearest-even
    return (ushort)(u >> 16);
}
__device__ inline float bf_lo(uint u) { return __uint_as_float(u << 16); }
__device__ inline float bf_hi(uint u) { return __uint_as_float(u & 0xffff0000u); }

// ---------------- degree / normalization ----------------

__global__ void k_init_deg(int* deg, int n) {
    int i = blockIdx.x * blockDim.x + threadIdx.x;
    if (i < n) deg[i] = 1;  // self-loop contributes 1
}

__global__ void k_count(const int* __restrict__ dst, int* __restrict__ deg, int e) {
    int i = blockIdx.x * blockDim.x + threadIdx.x;
    if (i < e) atomicAdd(&deg[dst[i]], 1);
}

__global__ void k_dis(const int* __restrict__ deg, float* __restrict__ dis, int n) {
    int i = blockIdx.x * blockDim.x + threadIdx.x;
    if (i < n) dis[i] = rsqrtf((float)deg[i]);
}

// ---------------- CSR build ----------------

__global__ __launch_bounds__(256) void k_scan1(const int* __restrict__ deg,
                                               int* __restrict__ offs,
                                               int* __restrict__ bsum, int n) {
    __shared__ int sh[256];
    int base = blockIdx.x * 1024;
    int t = threadIdx.x;
    int v[4];
    int sum = 0;
    #pragma unroll
    for (int j = 0; j < 4; ++j) {
        int i = base + t * 4 + j;
        int d = (i < n) ? (deg[i] - 1) : 0;
        v[j] = sum;
        sum += d;
    }
    sh[t] = sum;
    __syncthreads();
    #pragma unroll
    for (int off = 1; off < 256; off <<= 1) {
        int x = (t >= off) ? sh[t - off] : 0;
        __syncthreads();
        if (t >= off) sh[t] += x;
        __syncthreads();
    }
    int excl = (t == 0) ? 0 : sh[t - 1];
    if (t == 255) bsum[blockIdx.x] = sh[255];
    #pragma unroll
    for (int j = 0; j < 4; ++j) {
        int i = base + t * 4 + j;
        if (i < n) offs[i] = excl + v[j];
    }
}

__global__ __launch_bounds__(256) void k_scan2(int* __restrict__ bsum, int nb) {
    __shared__ int sh[256];
    int t = threadIdx.x;
    sh[t] = (t < nb) ? bsum[t] : 0;
    __syncthreads();
    #pragma unroll
    for (int off = 1; off < 256; off <<= 1) {
        int x = (t >= off) ? sh[t - off] : 0;
        __syncthreads();
        if (t >= off) sh[t] += x;
        __syncthreads();
    }
    int excl = (t == 0) ? 0 : sh[t - 1];
    if (t < nb) bsum[t] = excl;
}

__global__ void k_scan3(int* __restrict__ offs, int* __restrict__ cursor,
                        const int* __restrict__ bsum, int n) {
    int i = blockIdx.x * blockDim.x + threadIdx.x;
    if (i < n) {
        int o = offs[i] + bsum[i >> 10];
        offs[i] = o;
        cursor[i] = o;
    }
}

__global__ void k_fill(const int* __restrict__ src, const int* __restrict__ dst,
                       const float* __restrict__ dis, int* __restrict__ cursor,
                       int* __restrict__ adj, float* __restrict__ acoef, int e) {
    int i = blockIdx.x * blockDim.x + threadIdx.x;
    if (i >= e) return;
    int s = src[i], d = dst[i];
    int pos = atomicAdd(&cursor[d], 1);
    adj[pos] = s;
    acoef[pos] = dis[s] * dis[d];
}

// ---------------- GEMM1 (bf16 MFMA): h_bf16 = bf16(x) @ bf16(W1) ----------------
// 128 rows x 128 cols per block, 256 threads = 4 waves, each wave 32 rows x 128 cols.
// W1^T half-K staged in LDS [c][k] so B-fragments are contiguous short8 reads.

__global__ __launch_bounds__(256) void k_gemm1(
    const float* __restrict__ x, const float* __restrict__ W1,
    ushort* __restrict__ h, int n) {
    __shared__ union {
        ushort w1t[128][136];   // [col][k_local], pad to 272B rows (16B aligned)
        ushort cs[128][136];    // epilogue C staging (w1t dead by then)
    } u;
    __shared__ ushort xs[128][72];  // [row][k_local 0..63], 144B rows

    int tid = threadIdx.x;
    int row0 = blockIdx.x * 128;
    int lane = tid & 63;
    int w = tid >> 6;
    int wr0 = w * 32;
    int l15 = lane & 15;
    int koff = (lane >> 4) * 8;

    f32x4 acc[2][8];
    #pragma unroll
    for (int i = 0; i < 2; ++i)
        #pragma unroll
        for (int j = 0; j < 8; ++j)
            acc[i][j] = (f32x4){0.f, 0.f, 0.f, 0.f};

    for (int kh = 0; kh < 2; ++kh) {
        {   // stage W1^T half: w1t[c][kl] = W1[kh*128+kl][c]
            int kl = tid >> 1;
            int ch = (tid & 1) * 64;
            const float4* wr = (const float4*)(W1 + (size_t)(kh * 128 + kl) * DH + ch);
            #pragma unroll
            for (int c4 = 0; c4 < 16; ++c4) {
                float4 v = wr[c4];
                u.w1t[ch + c4 * 4 + 0][kl] = f2bf(v.x);
                u.w1t[ch + c4 * 4 + 1][kl] = f2bf(v.y);
                u.w1t[ch + c4 * 4 + 2][kl] = f2bf(v.z);
                u.w1t[ch + c4 * 4 + 3][kl] = f2bf(v.w);
            }
        }
        for (int kc2 = 0; kc2 < 2; ++kc2) {
            {   // stage x tile: 128 rows x 64 k (fp32 -> bf16)
                int r = tid >> 1;
                int half = (tid & 1) * 32;
                int rr = row0 + r; if (rr >= n) rr = n - 1;
                const float4* xr = (const float4*)(x + (size_t)rr * DIN + kh * 128 + kc2 * 64 + half);
                float4 v[8];
                #pragma unroll
                for (int q = 0; q < 8; ++q) v[q] = xr[q];
                #pragma unroll
                for (int q = 0; q < 8; ++q) {
                    ushort4 o;
                    o.x = f2bf(v[q].x); o.y = f2bf(v[q].y);
                    o.z = f2bf(v[q].z); o.w = f2bf(v[q].w);
                    *(ushort4*)&xs[r][half + q * 4] = o;
                }
            }
            __syncthreads();
            #pragma unroll
            for (int kk = 0; kk < 64; kk += 32) {
                s16x8 a0 = *(const s16x8*)&xs[wr0 + l15][kk + koff];
                s16x8 a1 = *(const s16x8*)&xs[wr0 + 16 + l15][kk + koff];
                int kl = kc2 * 64 + kk + koff;
                #pragma unroll
                for (int ct = 0; ct < 8; ++ct) {
                    s16x8 b = *(const s16x8*)&u.w1t[ct * 16 + l15][kl];
                    acc[0][ct] = __builtin_amdgcn_mfma_f32_16x16x32_bf16(a0, b, acc[0][ct], 0, 0, 0);
                    acc[1][ct] = __builtin_amdgcn_mfma_f32_16x16x32_bf16(a1, b, acc[1][ct], 0, 0, 0);
                }
            }
            __syncthreads();
        }
    }

    // epilogue: acc -> LDS (bf16, natural layout) -> coalesced global store
    #pragma unroll
    for (int rt = 0; rt < 2; ++rt)
        #pragma unroll
        for (int ct = 0; ct < 8; ++ct)
            #pragma unroll
            for (int r = 0; r < 4; ++r)
                u.cs[wr0 + rt * 16 + (lane >> 4) * 4 + r][ct * 16 + l15] = f2bf(acc[rt][ct][r]);
    __syncthreads();
    {
        int r = tid >> 1;
        int half = (tid & 1) * 64;
        if (row0 + r < n) {
            uint4* dstp = (uint4*)(h + (size_t)(row0 + r) * DH + half);
            const uint4* s = (const uint4*)&u.cs[r][half];
            #pragma unroll
            for (int q = 0; q < 8; ++q) dstp[q] = s[q];
        }
    }
}

// ---------------- agg1 (fused): h1 = relu( h*dis^2 + sum_nb h[s]*coef + b1 ) ----------
// one 64-lane wave per node; lane owns 2 columns (one uint = 2 bf16).

__global__ __launch_bounds__(256) void k_agg1(
    const ushort* __restrict__ h, const float* __restrict__ dis,
    const int* __restrict__ offs, const int* __restrict__ deg,
    const int* __restrict__ adj, const float* __restrict__ acoef,
    const float* __restrict__ b1, float* __restrict__ h1, int n) {
    int node = blockIdx.x * 4 + (threadIdx.x >> 6);
    if (node >= n) return;
    int lane = threadIdx.x & 63;
    const uint* hu = (const uint*)h;          // row stride 64 uints
    float dv = dis[node];
    float self = dv * dv;
    uint us = hu[(size_t)node * 64 + lane];
    float2 acc;
    acc.x = bf_lo(us) * self;
    acc.y = bf_hi(us) * self;

    int off = offs[node];
    int cnt = deg[node] - 1;
    int k = 0;
    for (; k + 1 < cnt; k += 2) {
        int s0 = adj[off + k], s1 = adj[off + k + 1];
        float c0 = acoef[off + k], c1 = acoef[off + k + 1];
        uint v0 = hu[(size_t)s0 * 64 + lane];
        uint v1 = hu[(size_t)s1 * 64 + lane];
        acc.x += bf_lo(v0) * c0 + bf_lo(v1) * c1;
        acc.y += bf_hi(v0) * c0 + bf_hi(v1) * c1;
    }
    if (k < cnt) {
        int s0 = adj[off + k];
        float c0 = acoef[off + k];
        uint v0 = hu[(size_t)s0 * 64 + lane];
        acc.x += bf_lo(v0) * c0;
        acc.y += bf_hi(v0) * c0;
    }
    float2 b = *(const float2*)(b1 + lane * 2);
    acc.x = fmaxf(acc.x + b.x, 0.f);
    acc.y = fmaxf(acc.y + b.y, 0.f);
    *(float2*)(h1 + (size_t)node * DH + lane * 2) = acc;
}

// ---------------- GEMM2: h2 = h1 @ W2 (fp32) ----------------

__global__ __launch_bounds__(256) void k_gemm2(
    const float* __restrict__ h1, const float* __restrict__ W2,
    float* __restrict__ h2, int n) {
    int t = blockIdx.x * blockDim.x + threadIdx.x;
    int row = t >> 3;
    int cg = t & 7;
    if (row >= n) return;
    const float4* hr = (const float4*)(h1 + (size_t)row * DH);
    const float4* w4 = (const float4*)W2;
    float4 acc = make_float4(0.f, 0.f, 0.f, 0.f);
    #pragma unroll 8
    for (int k4 = 0; k4 < DH / 4; ++k4) {
        float4 a = hr[k4];
        float4 w0 = w4[(k4 * 4 + 0) * 8 + cg];
        float4 w1 = w4[(k4 * 4 + 1) * 8 + cg];
        float4 w2 = w4[(k4 * 4 + 2) * 8 + cg];
        float4 w3 = w4[(k4 * 4 + 3) * 8 + cg];
        acc.x += a.x * w0.x + a.y * w1.x + a.z * w2.x + a.w * w3.x;
        acc.y += a.x * w0.y + a.y * w1.y + a.z * w2.y + a.w * w3.y;
        acc.z += a.x * w0.z + a.y * w1.z + a.z * w2.z + a.w * w3.z;
        acc.w += a.x * w0.w + a.y * w1.w + a.z * w2.w + a.w * w3.w;
    }
    ((float4*)h2)[(size_t)row * 8 + cg] = acc;
}

// ---------------- agg2 + bias + log_softmax fused ----------------

__global__ __launch_bounds__(256) void k_agg2_lsm(
    const float* __restrict__ h2, const float* __restrict__ dis,
    const int* __restrict__ offs, const int* __restrict__ deg,
    const int* __restrict__ adj, const float* __restrict__ acoef,
    const float* __restrict__ b2, float* __restrict__ out, int n) {
    int node = blockIdx.x * 8 + (threadIdx.x >> 5);
    if (node >= n) return;
    int c = threadIdx.x & 31;
    float dv = dis[node];
    float acc = h2[(size_t)node * DOUT + c] * dv * dv;

    int off = offs[node];
    int cnt = deg[node] - 1;
    int k = 0;
    for (; k + 1 < cnt; k += 2) {
        int s0 = adj[off + k], s1 = adj[off + k + 1];
        float c0 = acoef[off + k], c1 = acoef[off + k + 1];
        acc += h2[(size_t)s0 * DOUT + c] * c0 + h2[(size_t)s1 * DOUT + c] * c1;
    }
    if (k < cnt) {
        acc += h2[(size_t)adj[off + k] * DOUT + c] * acoef[off + k];
    }
    float v = acc + b2[c];
    float m = v;
    #pragma unroll
    for (int o = 16; o > 0; o >>= 1) m = fmaxf(m, __shfl_xor(m, o));
    float ev = __expf(v - m);
    float s = ev;
    #pragma unroll
    for (int o = 16; o > 0; o >>= 1) s += __shfl_xor(s, o);
    out[(size_t)node * DOUT + c] = v - m - __logf(s);
}

extern "C" void kernel_launch(void* const* d_in, const int* in_sizes, int n_in,
                              void* d_out, int out_size, void* d_ws, size_t ws_size,
                              hipStream_t stream) {
    const float* x  = (const float*)d_in[0];
    const int*   ei = (const int*)d_in[1];
    const float* W1 = (const float*)d_in[2];
    const float* b1 = (const float*)d_in[3];
    const float* W2 = (const float*)d_in[4];
    const float* b2 = (const float*)d_in[5];
    int n = in_sizes[0] / DIN;
    int e = in_sizes[1] / 2;
    const int* src = ei;
    const int* dst = ei + e;
    float* out = (float*)d_out;

    // workspace: deg|offs|cursor|bsum|dis|adj|acoef|h(bf16)|h1(f32)|h2(f32)  ~104 MB
    char* p = (char*)d_ws;
    int*    deg    = (int*)p;     p += (size_t)n * 4;
    int*    offs   = (int*)p;     p += (size_t)n * 4;
    int*    cursor = (int*)p;     p += (size_t)n * 4;
    int*    bsum   = (int*)p;     p += 1024;
    float*  dis    = (float*)p;   p += (size_t)n * 4;
    int*    adj    = (int*)p;     p += (size_t)e * 4;
    float*  acoef  = (float*)p;   p += (size_t)e * 4;
    ushort* h      = (ushort*)p;  p += (size_t)n * DH * 2;
    float*  h1     = (float*)p;   p += (size_t)n * DH * 4;
    float*  h2     = (float*)p;

    int nb = (n + 1023) / 1024;

    k_init_deg<<<(n + 255) / 256, 256, 0, stream>>>(deg, n);
    k_count<<<(e + 255) / 256, 256, 0, stream>>>(dst, deg, e);
    k_dis<<<(n + 255) / 256, 256, 0, stream>>>(deg, dis, n);
    k_scan1<<<nb, 256, 0, stream>>>(deg, offs, bsum, n);
    k_scan2<<<1, 256, 0, stream>>>(bsum, nb);
    k_scan3<<<(n + 255) / 256, 256, 0, stream>>>(offs, cursor, bsum, n);
    k_fill<<<(e + 255) / 256, 256, 0, stream>>>(src, dst, dis, cursor, adj, acoef, e);

    k_gemm1<<<(n + 127) / 128, 256, 0, stream>>>(x, W1, h, n);
    k_agg1<<<(n + 3) / 4, 256, 0, stream>>>(h, dis, offs, deg, adj, acoef, b1, h1, n);
    k_gemm2<<<(n * 8 + 255) / 256, 256, 0, stream>>>(h1, W2, h2, n);
    k_agg2_lsm<<<(n + 7) / 8, 256, 0, stream>>>(h2, dis, offs, deg, adj, acoef, b2, out, n);
}

// Round 4
// 431.845 us; speedup vs baseline: 4.1779x; 1.0887x over previous
//
#include <hip/hip_runtime.h>
#include <cstdint>

#define DIN 256
#define DH 128
#define DOUT 32

typedef short s16x8 __attribute__((ext_vector_type(8)));
typedef float f32x4 __attribute__((ext_vector_type(4)));

__device__ inline ushort f2bf(float f) {
    uint u = __float_as_uint(f);
    u += 0x7fff + ((u >> 16) & 1);   // round-to-nearest-even
    return (ushort)(u >> 16);
}
__device__ inline float bf_lo(uint u) { return __uint_as_float(u << 16); }
__device__ inline float bf_hi(uint u) { return __uint_as_float(u & 0xffff0000u); }
__device__ inline float bfs(ushort u) { return __uint_as_float((uint)u << 16); }

// ---------------- degree / normalization ----------------

__global__ void k_init_deg(int* deg, int n) {
    int i = blockIdx.x * blockDim.x + threadIdx.x;
    if (i < n) deg[i] = 1;  // self-loop contributes 1
}

__global__ void k_count(const int* __restrict__ dst, int* __restrict__ deg, int e) {
    int i = blockIdx.x * blockDim.x + threadIdx.x;
    if (i < e) atomicAdd(&deg[dst[i]], 1);
}

__global__ void k_dis(const int* __restrict__ deg, float* __restrict__ dis, int n) {
    int i = blockIdx.x * blockDim.x + threadIdx.x;
    if (i < n) dis[i] = rsqrtf((float)deg[i]);
}

// ---------------- CSR build ----------------

__global__ __launch_bounds__(256) void k_scan1(const int* __restrict__ deg,
                                               int* __restrict__ offs,
                                               int* __restrict__ bsum, int n) {
    __shared__ int sh[256];
    int base = blockIdx.x * 1024;
    int t = threadIdx.x;
    int v[4];
    int sum = 0;
    #pragma unroll
    for (int j = 0; j < 4; ++j) {
        int i = base + t * 4 + j;
        int d = (i < n) ? (deg[i] - 1) : 0;
        v[j] = sum;
        sum += d;
    }
    sh[t] = sum;
    __syncthreads();
    #pragma unroll
    for (int off = 1; off < 256; off <<= 1) {
        int x = (t >= off) ? sh[t - off] : 0;
        __syncthreads();
        if (t >= off) sh[t] += x;
        __syncthreads();
    }
    int excl = (t == 0) ? 0 : sh[t - 1];
    if (t == 255) bsum[blockIdx.x] = sh[255];
    #pragma unroll
    for (int j = 0; j < 4; ++j) {
        int i = base + t * 4 + j;
        if (i < n) offs[i] = excl + v[j];
    }
}

__global__ __launch_bounds__(256) void k_scan2(int* __restrict__ bsum, int nb) {
    __shared__ int sh[256];
    int t = threadIdx.x;
    sh[t] = (t < nb) ? bsum[t] : 0;
    __syncthreads();
    #pragma unroll
    for (int off = 1; off < 256; off <<= 1) {
        int x = (t >= off) ? sh[t - off] : 0;
        __syncthreads();
        if (t >= off) sh[t] += x;
        __syncthreads();
    }
    int excl = (t == 0) ? 0 : sh[t - 1];
    if (t < nb) bsum[t] = excl;
}

__global__ void k_scan3(int* __restrict__ offs, int* __restrict__ cursor,
                        const int* __restrict__ bsum, int n) {
    int i = blockIdx.x * blockDim.x + threadIdx.x;
    if (i < n) {
        int o = offs[i] + bsum[i >> 10];
        offs[i] = o;
        cursor[i] = o;
    }
}

__global__ void k_fill(const int* __restrict__ src, const int* __restrict__ dst,
                       int* __restrict__ cursor, int* __restrict__ adj, int e) {
    int i = blockIdx.x * blockDim.x + threadIdx.x;
    if (i >= e) return;
    int s = src[i], d = dst[i];
    int pos = atomicAdd(&cursor[d], 1);
    adj[pos] = s;
}

// ---------------- GEMM1 (bf16 MFMA): hs = bf16( (x @ W1) * dis[row] ) ----------------
// 128x128 tile, 256 threads = 4 waves, each wave 32 rows x 128 cols.

__global__ __launch_bounds__(256) void k_gemm1(
    const float* __restrict__ x, const float* __restrict__ W1,
    const float* __restrict__ dis, ushort* __restrict__ hs, int n) {
    __shared__ union {
        ushort w1t[128][136];   // [col][k_local]
        ushort cs[128][136];    // epilogue staging
    } u;
    __shared__ ushort xs[128][72];

    int tid = threadIdx.x;
    int row0 = blockIdx.x * 128;
    int lane = tid & 63;
    int w = tid >> 6;
    int wr0 = w * 32;
    int l15 = lane & 15;
    int koff = (lane >> 4) * 8;

    f32x4 acc[2][8];
    #pragma unroll
    for (int i = 0; i < 2; ++i)
        #pragma unroll
        for (int j = 0; j < 8; ++j)
            acc[i][j] = (f32x4){0.f, 0.f, 0.f, 0.f};

    for (int kh = 0; kh < 2; ++kh) {
        {   // stage W1^T half: w1t[c][kl] = W1[kh*128+kl][c]
            int kl = tid >> 1;
            int ch = (tid & 1) * 64;
            const float4* wr = (const float4*)(W1 + (size_t)(kh * 128 + kl) * DH + ch);
            #pragma unroll
            for (int c4 = 0; c4 < 16; ++c4) {
                float4 v = wr[c4];
                u.w1t[ch + c4 * 4 + 0][kl] = f2bf(v.x);
                u.w1t[ch + c4 * 4 + 1][kl] = f2bf(v.y);
                u.w1t[ch + c4 * 4 + 2][kl] = f2bf(v.z);
                u.w1t[ch + c4 * 4 + 3][kl] = f2bf(v.w);
            }
        }
        for (int kc2 = 0; kc2 < 2; ++kc2) {
            {   // stage x tile: 128 rows x 64 k (fp32 -> bf16)
                int r = tid >> 1;
                int half = (tid & 1) * 32;
                int rr = row0 + r; if (rr >= n) rr = n - 1;
                const float4* xr = (const float4*)(x + (size_t)rr * DIN + kh * 128 + kc2 * 64 + half);
                float4 v[8];
                #pragma unroll
                for (int q = 0; q < 8; ++q) v[q] = xr[q];
                #pragma unroll
                for (int q = 0; q < 8; ++q) {
                    ushort4 o;
                    o.x = f2bf(v[q].x); o.y = f2bf(v[q].y);
                    o.z = f2bf(v[q].z); o.w = f2bf(v[q].w);
                    *(ushort4*)&xs[r][half + q * 4] = o;
                }
            }
            __syncthreads();
            #pragma unroll
            for (int kk = 0; kk < 64; kk += 32) {
                s16x8 a0 = *(const s16x8*)&xs[wr0 + l15][kk + koff];
                s16x8 a1 = *(const s16x8*)&xs[wr0 + 16 + l15][kk + koff];
                int kl = kc2 * 64 + kk + koff;
                #pragma unroll
                for (int ct = 0; ct < 8; ++ct) {
                    s16x8 b = *(const s16x8*)&u.w1t[ct * 16 + l15][kl];
                    acc[0][ct] = __builtin_amdgcn_mfma_f32_16x16x32_bf16(a0, b, acc[0][ct], 0, 0, 0);
                    acc[1][ct] = __builtin_amdgcn_mfma_f32_16x16x32_bf16(a1, b, acc[1][ct], 0, 0, 0);
                }
            }
            __syncthreads();
        }
    }

    // epilogue: scale by dis[row], pack bf16, stage through LDS, coalesced store
    float dv[2][4];
    #pragma unroll
    for (int rt = 0; rt < 2; ++rt)
        #pragma unroll
        for (int r = 0; r < 4; ++r) {
            int rg = row0 + wr0 + rt * 16 + (lane >> 4) * 4 + r;
            if (rg >= n) rg = n - 1;
            dv[rt][r] = dis[rg];
        }
    #pragma unroll
    for (int rt = 0; rt < 2; ++rt)
        #pragma unroll
        for (int ct = 0; ct < 8; ++ct)
            #pragma unroll
            for (int r = 0; r < 4; ++r)
                u.cs[wr0 + rt * 16 + (lane >> 4) * 4 + r][ct * 16 + l15] = f2bf(acc[rt][ct][r] * dv[rt][r]);
    __syncthreads();
    {
        int r = tid >> 1;
        int half = (tid & 1) * 64;
        if (row0 + r < n) {
            uint4* dstp = (uint4*)(hs + (size_t)(row0 + r) * DH + half);
            const uint4* s = (const uint4*)&u.cs[r][half];
            #pragma unroll
            for (int q = 0; q < 8; ++q) dstp[q] = s[q];
        }
    }
}

// ---------------- agg1 (fused): h1 = bf16(relu( dis[d]*(hs[d]+sum_nb hs[s]) + b1 )) ----
// one 64-lane wave per node; lane owns 2 columns.

__global__ __launch_bounds__(256) void k_agg1(
    const ushort* __restrict__ hs, const float* __restrict__ dis,
    const int* __restrict__ offs, const int* __restrict__ deg,
    const int* __restrict__ adj, const float* __restrict__ b1,
    ushort* __restrict__ h1, int n) {
    int node = blockIdx.x * 4 + (threadIdx.x >> 6);
    if (node >= n) return;
    int lane = threadIdx.x & 63;
    const uint* hu = (const uint*)hs;          // row stride 64 uints
    uint us = hu[(size_t)node * 64 + lane];
    float2 acc;
    acc.x = bf_lo(us);
    acc.y = bf_hi(us);

    int off = offs[node];
    int cnt = deg[node] - 1;
    int k = 0;
    for (; k + 3 < cnt; k += 4) {
        int s0 = adj[off + k], s1 = adj[off + k + 1];
        int s2 = adj[off + k + 2], s3 = adj[off + k + 3];
        uint v0 = hu[(size_t)s0 * 64 + lane];
        uint v1 = hu[(size_t)s1 * 64 + lane];
        uint v2 = hu[(size_t)s2 * 64 + lane];
        uint v3 = hu[(size_t)s3 * 64 + lane];
        acc.x += bf_lo(v0) + bf_lo(v1) + bf_lo(v2) + bf_lo(v3);
        acc.y += bf_hi(v0) + bf_hi(v1) + bf_hi(v2) + bf_hi(v3);
    }
    for (; k < cnt; ++k) {
        uint v0 = hu[(size_t)adj[off + k] * 64 + lane];
        acc.x += bf_lo(v0);
        acc.y += bf_hi(v0);
    }
    float dv = dis[node];
    float2 b = *(const float2*)(b1 + lane * 2);
    float rx = fmaxf(acc.x * dv + b.x, 0.f);
    float ry = fmaxf(acc.y * dv + b.y, 0.f);
    uint po = (uint)f2bf(rx) | ((uint)f2bf(ry) << 16);
    ((uint*)h1)[(size_t)node * 64 + lane] = po;
}

// ---------------- GEMM2: h2s = bf16( (h1 @ W2) * dis[row] ) ----------------

__global__ __launch_bounds__(256) void k_gemm2(
    const ushort* __restrict__ h1, const float* __restrict__ W2,
    const float* __restrict__ dis, ushort* __restrict__ h2s, int n) {
    int t = blockIdx.x * blockDim.x + threadIdx.x;
    int row = t >> 3;
    int cg = t & 7;
    if (row >= n) return;
    const uint2* hr = (const uint2*)(h1 + (size_t)row * DH);  // 4 bf16 per uint2
    const float4* w4 = (const float4*)W2;
    float4 acc = make_float4(0.f, 0.f, 0.f, 0.f);
    #pragma unroll 8
    for (int k4 = 0; k4 < DH / 4; ++k4) {
        uint2 au = hr[k4];
        float a0 = bf_lo(au.x), a1 = bf_hi(au.x), a2 = bf_lo(au.y), a3 = bf_hi(au.y);
        float4 w0 = w4[(k4 * 4 + 0) * 8 + cg];
        float4 w1 = w4[(k4 * 4 + 1) * 8 + cg];
        float4 w2 = w4[(k4 * 4 + 2) * 8 + cg];
        float4 w3 = w4[(k4 * 4 + 3) * 8 + cg];
        acc.x += a0 * w0.x + a1 * w1.x + a2 * w2.x + a3 * w3.x;
        acc.y += a0 * w0.y + a1 * w1.y + a2 * w2.y + a3 * w3.y;
        acc.z += a0 * w0.z + a1 * w1.z + a2 * w2.z + a3 * w3.z;
        acc.w += a0 * w0.w + a1 * w1.w + a2 * w2.w + a3 * w3.w;
    }
    float dv = dis[row];
    ushort4 o;
    o.x = f2bf(acc.x * dv); o.y = f2bf(acc.y * dv);
    o.z = f2bf(acc.z * dv); o.w = f2bf(acc.w * dv);
    *(ushort4*)(h2s + (size_t)row * DOUT + cg * 4) = o;
}

// ---------------- agg2 + bias + log_softmax fused ----------------
// 32 threads per node; lane owns 1 column.

__global__ __launch_bounds__(256) void k_agg2_lsm(
    const ushort* __restrict__ h2s, const float* __restrict__ dis,
    const int* __restrict__ offs, const int* __restrict__ deg,
    const int* __restrict__ adj, const float* __restrict__ b2,
    float* __restrict__ out, int n) {
    int node = blockIdx.x * 8 + (threadIdx.x >> 5);
    if (node >= n) return;
    int c = threadIdx.x & 31;
    float acc = bfs(h2s[(size_t)node * DOUT + c]);

    int off = offs[node];
    int cnt = deg[node] - 1;
    int k = 0;
    for (; k + 3 < cnt; k += 4) {
        int s0 = adj[off + k], s1 = adj[off + k + 1];
        int s2 = adj[off + k + 2], s3 = adj[off + k + 3];
        acc += bfs(h2s[(size_t)s0 * DOUT + c]) + bfs(h2s[(size_t)s1 * DOUT + c])
             + bfs(h2s[(size_t)s2 * DOUT + c]) + bfs(h2s[(size_t)s3 * DOUT + c]);
    }
    for (; k < cnt; ++k) {
        acc += bfs(h2s[(size_t)adj[off + k] * DOUT + c]);
    }
    float v = acc * dis[node] + b2[c];
    float m = v;
    #pragma unroll
    for (int o = 16; o > 0; o >>= 1) m = fmaxf(m, __shfl_xor(m, o));
    float ev = __expf(v - m);
    float s = ev;
    #pragma unroll
    for (int o = 16; o > 0; o >>= 1) s += __shfl_xor(s, o);
    out[(size_t)node * DOUT + c] = v - m - __logf(s);
}

extern "C" void kernel_launch(void* const* d_in, const int* in_sizes, int n_in,
                              void* d_out, int out_size, void* d_ws, size_t ws_size,
                              hipStream_t stream) {
    const float* x  = (const float*)d_in[0];
    const int*   ei = (const int*)d_in[1];
    const float* W1 = (const float*)d_in[2];
    const float* b1 = (const float*)d_in[3];
    const float* W2 = (const float*)d_in[4];
    const float* b2 = (const float*)d_in[5];
    int n = in_sizes[0] / DIN;
    int e = in_sizes[1] / 2;
    const int* src = ei;
    const int* dst = ei + e;
    float* out = (float*)d_out;

    // workspace: deg|offs|cursor|bsum|dis|adj|hs(bf16)|h1(bf16)|h2s(bf16)  ~66 MB
    char* p = (char*)d_ws;
    int*    deg    = (int*)p;     p += (size_t)n * 4;
    int*    offs   = (int*)p;     p += (size_t)n * 4;
    int*    cursor = (int*)p;     p += (size_t)n * 4;
    int*    bsum   = (int*)p;     p += 1024;
    float*  dis    = (float*)p;   p += (size_t)n * 4;
    int*    adj    = (int*)p;     p += (size_t)e * 4;
    ushort* hs     = (ushort*)p;  p += (size_t)n * DH * 2;
    ushort* h1     = (ushort*)p;  p += (size_t)n * DH * 2;
    ushort* h2s    = (ushort*)p;

    int nb = (n + 1023) / 1024;

    k_init_deg<<<(n + 255) / 256, 256, 0, stream>>>(deg, n);
    k_count<<<(e + 255) / 256, 256, 0, stream>>>(dst, deg, e);
    k_dis<<<(n + 255) / 256, 256, 0, stream>>>(deg, dis, n);
    k_scan1<<<nb, 256, 0, stream>>>(deg, offs, bsum, n);
    k_scan2<<<1, 256, 0, stream>>>(bsum, nb);
    k_scan3<<<(n + 255) / 256, 256, 0, stream>>>(offs, cursor, bsum, n);
    k_fill<<<(e + 255) / 256, 256, 0, stream>>>(src, dst, cursor, adj, e);

    k_gemm1<<<(n + 127) / 128, 256, 0, stream>>>(x, W1, dis, hs, n);
    k_agg1<<<(n + 3) / 4, 256, 0, stream>>>(hs, dis, offs, deg, adj, b1, h1, n);
    k_gemm2<<<(n * 8 + 255) / 256, 256, 0, stream>>>(h1, W2, dis, h2s, n);
    k_agg2_lsm<<<(n + 7) / 8, 256, 0, stream>>>(h2s, dis, offs, deg, adj, b2, out, n);
}

// Round 5
// 373.344 us; speedup vs baseline: 4.8326x; 1.1567x over previous
//
#include <hip/hip_runtime.h>
#include <cstdint>

#define DIN 256
#define DH 128
#define DOUT 32

typedef short s16x8 __attribute__((ext_vector_type(8)));
typedef float f32x4 __attribute__((ext_vector_type(4)));

__device__ inline ushort f2bf(float f) {
    uint u = __float_as_uint(f);
    u += 0x7fff + ((u >> 16) & 1);   // round-to-nearest-even
    return (ushort)(u >> 16);
}
__device__ inline float bf_lo(uint u) { return __uint_as_float(u << 16); }
__device__ inline float bf_hi(uint u) { return __uint_as_float(u & 0xffff0000u); }
__device__ inline float bfs(ushort u) { return __uint_as_float((uint)u << 16); }

// ---------------- degree / normalization ----------------

__global__ void k_init_deg(int* deg, int n) {
    int i = blockIdx.x * blockDim.x + threadIdx.x;
    if (i < n) deg[i] = 1;  // self-loop contributes 1
}

__global__ void k_count(const int* __restrict__ dst, int* __restrict__ deg, int e) {
    int i = blockIdx.x * blockDim.x + threadIdx.x;
    if (i < e) atomicAdd(&deg[dst[i]], 1);
}

__global__ void k_dis(const int* __restrict__ deg, float* __restrict__ dis, int n) {
    int i = blockIdx.x * blockDim.x + threadIdx.x;
    if (i < n) dis[i] = rsqrtf((float)deg[i]);
}

// ---------------- CSR build ----------------

__global__ __launch_bounds__(256) void k_scan1(const int* __restrict__ deg,
                                               int* __restrict__ offs,
                                               int* __restrict__ bsum, int n) {
    __shared__ int sh[256];
    int base = blockIdx.x * 1024;
    int t = threadIdx.x;
    int v[4];
    int sum = 0;
    #pragma unroll
    for (int j = 0; j < 4; ++j) {
        int i = base + t * 4 + j;
        int d = (i < n) ? (deg[i] - 1) : 0;
        v[j] = sum;
        sum += d;
    }
    sh[t] = sum;
    __syncthreads();
    #pragma unroll
    for (int off = 1; off < 256; off <<= 1) {
        int x = (t >= off) ? sh[t - off] : 0;
        __syncthreads();
        if (t >= off) sh[t] += x;
        __syncthreads();
    }
    int excl = (t == 0) ? 0 : sh[t - 1];
    if (t == 255) bsum[blockIdx.x] = sh[255];
    #pragma unroll
    for (int j = 0; j < 4; ++j) {
        int i = base + t * 4 + j;
        if (i < n) offs[i] = excl + v[j];
    }
}

__global__ __launch_bounds__(256) void k_scan2(int* __restrict__ bsum, int nb) {
    __shared__ int sh[256];
    int t = threadIdx.x;
    sh[t] = (t < nb) ? bsum[t] : 0;
    __syncthreads();
    #pragma unroll
    for (int off = 1; off < 256; off <<= 1) {
        int x = (t >= off) ? sh[t - off] : 0;
        __syncthreads();
        if (t >= off) sh[t] += x;
        __syncthreads();
    }
    int excl = (t == 0) ? 0 : sh[t - 1];
    if (t < nb) bsum[t] = excl;
}

__global__ void k_scan3(int* __restrict__ offs, int* __restrict__ cursor,
                        const int* __restrict__ bsum, int n) {
    int i = blockIdx.x * blockDim.x + threadIdx.x;
    if (i < n) {
        int o = offs[i] + bsum[i >> 10];
        offs[i] = o;
        cursor[i] = o;
    }
}

// ---------------- fill: XCD-ownership partitioned by dst range ----------------
// blocks round-robin across 8 XCDs => blockIdx&7 groups co-resident blocks.
// Range r owns dst in [r*n/8, (r+1)*n/8): its adj/cursor window (~850KB) stays
// in ONE XCD's L2 and accumulates all its 4B writes before writeback.

__global__ __launch_bounds__(256) void k_fill(
    const int* __restrict__ src, const int* __restrict__ dst,
    int* __restrict__ cursor, int* __restrict__ adj, int e, int n) {
    int r = blockIdx.x & 7;
    int q = blockIdx.x >> 3;
    int nq = gridDim.x >> 3;
    int lo = (int)((long long)n * r >> 3);
    int hi = (int)((long long)n * (r + 1) >> 3);
    for (int i = q * blockDim.x + threadIdx.x; i < e; i += nq * blockDim.x) {
        int d = dst[i];
        if (d < lo || d >= hi) continue;
        int s = src[i];
        int pos = atomicAdd(&cursor[d], 1);
        adj[pos] = s;
    }
}

// ---------------- GEMM1 (bf16 MFMA): hs = bf16( (x @ W1) * dis[row] ) ----------------

__global__ __launch_bounds__(256) void k_gemm1(
    const float* __restrict__ x, const float* __restrict__ W1,
    const float* __restrict__ dis, ushort* __restrict__ hs, int n) {
    __shared__ union {
        ushort w1t[128][136];   // [col][k_local]
        ushort cs[128][136];    // epilogue staging
    } u;
    __shared__ ushort xs[128][72];

    int tid = threadIdx.x;
    int row0 = blockIdx.x * 128;
    int lane = tid & 63;
    int w = tid >> 6;
    int wr0 = w * 32;
    int l15 = lane & 15;
    int koff = (lane >> 4) * 8;

    f32x4 acc[2][8];
    #pragma unroll
    for (int i = 0; i < 2; ++i)
        #pragma unroll
        for (int j = 0; j < 8; ++j)
            acc[i][j] = (f32x4){0.f, 0.f, 0.f, 0.f};

    for (int kh = 0; kh < 2; ++kh) {
        {   // stage W1^T half: w1t[c][kl] = W1[kh*128+kl][c]
            int kl = tid >> 1;
            int ch = (tid & 1) * 64;
            const float4* wr = (const float4*)(W1 + (size_t)(kh * 128 + kl) * DH + ch);
            #pragma unroll
            for (int c4 = 0; c4 < 16; ++c4) {
                float4 v = wr[c4];
                u.w1t[ch + c4 * 4 + 0][kl] = f2bf(v.x);
                u.w1t[ch + c4 * 4 + 1][kl] = f2bf(v.y);
                u.w1t[ch + c4 * 4 + 2][kl] = f2bf(v.z);
                u.w1t[ch + c4 * 4 + 3][kl] = f2bf(v.w);
            }
        }
        for (int kc2 = 0; kc2 < 2; ++kc2) {
            {   // stage x tile: 128 rows x 64 k (fp32 -> bf16)
                int r = tid >> 1;
                int half = (tid & 1) * 32;
                int rr = row0 + r; if (rr >= n) rr = n - 1;
                const float4* xr = (const float4*)(x + (size_t)rr * DIN + kh * 128 + kc2 * 64 + half);
                float4 v[8];
                #pragma unroll
                for (int q = 0; q < 8; ++q) v[q] = xr[q];
                #pragma unroll
                for (int q = 0; q < 8; ++q) {
                    ushort4 o;
                    o.x = f2bf(v[q].x); o.y = f2bf(v[q].y);
                    o.z = f2bf(v[q].z); o.w = f2bf(v[q].w);
                    *(ushort4*)&xs[r][half + q * 4] = o;
                }
            }
            __syncthreads();
            #pragma unroll
            for (int kk = 0; kk < 64; kk += 32) {
                s16x8 a0 = *(const s16x8*)&xs[wr0 + l15][kk + koff];
                s16x8 a1 = *(const s16x8*)&xs[wr0 + 16 + l15][kk + koff];
                int kl = kc2 * 64 + kk + koff;
                #pragma unroll
                for (int ct = 0; ct < 8; ++ct) {
                    s16x8 b = *(const s16x8*)&u.w1t[ct * 16 + l15][kl];
                    acc[0][ct] = __builtin_amdgcn_mfma_f32_16x16x32_bf16(a0, b, acc[0][ct], 0, 0, 0);
                    acc[1][ct] = __builtin_amdgcn_mfma_f32_16x16x32_bf16(a1, b, acc[1][ct], 0, 0, 0);
                }
            }
            __syncthreads();
        }
    }

    // epilogue: scale by dis[row], pack bf16, stage through LDS, coalesced store
    float dv[2][4];
    #pragma unroll
    for (int rt = 0; rt < 2; ++rt)
        #pragma unroll
        for (int r = 0; r < 4; ++r) {
            int rg = row0 + wr0 + rt * 16 + (lane >> 4) * 4 + r;
            if (rg >= n) rg = n - 1;
            dv[rt][r] = dis[rg];
        }
    #pragma unroll
    for (int rt = 0; rt < 2; ++rt)
        #pragma unroll
        for (int ct = 0; ct < 8; ++ct)
            #pragma unroll
            for (int r = 0; r < 4; ++r)
                u.cs[wr0 + rt * 16 + (lane >> 4) * 4 + r][ct * 16 + l15] = f2bf(acc[rt][ct][r] * dv[rt][r]);
    __syncthreads();
    {
        int r = tid >> 1;
        int half = (tid & 1) * 64;
        if (row0 + r < n) {
            uint4* dstp = (uint4*)(hs + (size_t)(row0 + r) * DH + half);
            const uint4* s = (const uint4*)&u.cs[r][half];
            #pragma unroll
            for (int q = 0; q < 8; ++q) dstp[q] = s[q];
        }
    }
}

// ---------------- agg1 (fused): h1 = bf16(relu( dis[d]*(hs[d]+sum_nb hs[s]) + b1 )) ----

__global__ __launch_bounds__(256) void k_agg1(
    const ushort* __restrict__ hs, const float* __restrict__ dis,
    const int* __restrict__ offs, const int* __restrict__ deg,
    const int* __restrict__ adj, const float* __restrict__ b1,
    ushort* __restrict__ h1, int n) {
    int node = blockIdx.x * 4 + (threadIdx.x >> 6);
    if (node >= n) return;
    int lane = threadIdx.x & 63;
    const uint* hu = (const uint*)hs;          // row stride 64 uints
    uint us = hu[(size_t)node * 64 + lane];
    float2 acc;
    acc.x = bf_lo(us);
    acc.y = bf_hi(us);

    int off = offs[node];
    int cnt = deg[node] - 1;
    int k = 0;
    for (; k + 3 < cnt; k += 4) {
        int s0 = adj[off + k], s1 = adj[off + k + 1];
        int s2 = adj[off + k + 2], s3 = adj[off + k + 3];
        uint v0 = hu[(size_t)s0 * 64 + lane];
        uint v1 = hu[(size_t)s1 * 64 + lane];
        uint v2 = hu[(size_t)s2 * 64 + lane];
        uint v3 = hu[(size_t)s3 * 64 + lane];
        acc.x += bf_lo(v0) + bf_lo(v1) + bf_lo(v2) + bf_lo(v3);
        acc.y += bf_hi(v0) + bf_hi(v1) + bf_hi(v2) + bf_hi(v3);
    }
    for (; k < cnt; ++k) {
        uint v0 = hu[(size_t)adj[off + k] * 64 + lane];
        acc.x += bf_lo(v0);
        acc.y += bf_hi(v0);
    }
    float dv = dis[node];
    float2 b = *(const float2*)(b1 + lane * 2);
    float rx = fmaxf(acc.x * dv + b.x, 0.f);
    float ry = fmaxf(acc.y * dv + b.y, 0.f);
    uint po = (uint)f2bf(rx) | ((uint)f2bf(ry) << 16);
    ((uint*)h1)[(size_t)node * 64 + lane] = po;
}

// ---------------- GEMM2: h2s = bf16( (h1 @ W2) * dis[row] ) ----------------

__global__ __launch_bounds__(256) void k_gemm2(
    const ushort* __restrict__ h1, const float* __restrict__ W2,
    const float* __restrict__ dis, ushort* __restrict__ h2s, int n) {
    int t = blockIdx.x * blockDim.x + threadIdx.x;
    int row = t >> 3;
    int cg = t & 7;
    if (row >= n) return;
    const uint2* hr = (const uint2*)(h1 + (size_t)row * DH);
    const float4* w4 = (const float4*)W2;
    float4 acc = make_float4(0.f, 0.f, 0.f, 0.f);
    #pragma unroll 8
    for (int k4 = 0; k4 < DH / 4; ++k4) {
        uint2 au = hr[k4];
        float a0 = bf_lo(au.x), a1 = bf_hi(au.x), a2 = bf_lo(au.y), a3 = bf_hi(au.y);
        float4 w0 = w4[(k4 * 4 + 0) * 8 + cg];
        float4 w1 = w4[(k4 * 4 + 1) * 8 + cg];
        float4 w2 = w4[(k4 * 4 + 2) * 8 + cg];
        float4 w3 = w4[(k4 * 4 + 3) * 8 + cg];
        acc.x += a0 * w0.x + a1 * w1.x + a2 * w2.x + a3 * w3.x;
        acc.y += a0 * w0.y + a1 * w1.y + a2 * w2.y + a3 * w3.y;
        acc.z += a0 * w0.z + a1 * w1.z + a2 * w2.z + a3 * w3.z;
        acc.w += a0 * w0.w + a1 * w1.w + a2 * w2.w + a3 * w3.w;
    }
    float dv = dis[row];
    ushort4 o;
    o.x = f2bf(acc.x * dv); o.y = f2bf(acc.y * dv);
    o.z = f2bf(acc.z * dv); o.w = f2bf(acc.w * dv);
    *(ushort4*)(h2s + (size_t)row * DOUT + cg * 4) = o;
}

// ---------------- agg2 + bias + log_softmax fused ----------------

__global__ __launch_bounds__(256) void k_agg2_lsm(
    const ushort* __restrict__ h2s, const float* __restrict__ dis,
    const int* __restrict__ offs, const int* __restrict__ deg,
    const int* __restrict__ adj, const float* __restrict__ b2,
    float* __restrict__ out, int n) {
    int node = blockIdx.x * 8 + (threadIdx.x >> 5);
    if (node >= n) return;
    int c = threadIdx.x & 31;
    float acc = bfs(h2s[(size_t)node * DOUT + c]);

    int off = offs[node];
    int cnt = deg[node] - 1;
    int k = 0;
    for (; k + 3 < cnt; k += 4) {
        int s0 = adj[off + k], s1 = adj[off + k + 1];
        int s2 = adj[off + k + 2], s3 = adj[off + k + 3];
        acc += bfs(h2s[(size_t)s0 * DOUT + c]) + bfs(h2s[(size_t)s1 * DOUT + c])
             + bfs(h2s[(size_t)s2 * DOUT + c]) + bfs(h2s[(size_t)s3 * DOUT + c]);
    }
    for (; k < cnt; ++k) {
        acc += bfs(h2s[(size_t)adj[off + k] * DOUT + c]);
    }
    float v = acc * dis[node] + b2[c];
    float m = v;
    #pragma unroll
    for (int o = 16; o > 0; o >>= 1) m = fmaxf(m, __shfl_xor(m, o));
    float ev = __expf(v - m);
    float s = ev;
    #pragma unroll
    for (int o = 16; o > 0; o >>= 1) s += __shfl_xor(s, o);
    out[(size_t)node * DOUT + c] = v - m - __logf(s);
}

extern "C" void kernel_launch(void* const* d_in, const int* in_sizes, int n_in,
                              void* d_out, int out_size, void* d_ws, size_t ws_size,
                              hipStream_t stream) {
    const float* x  = (const float*)d_in[0];
    const int*   ei = (const int*)d_in[1];
    const float* W1 = (const float*)d_in[2];
    const float* b1 = (const float*)d_in[3];
    const float* W2 = (const float*)d_in[4];
    const float* b2 = (const float*)d_in[5];
    int n = in_sizes[0] / DIN;
    int e = in_sizes[1] / 2;
    const int* src = ei;
    const int* dst = ei + e;
    float* out = (float*)d_out;

    // workspace: deg|offs|cursor|bsum|dis|adj|hs(bf16)|h1(bf16)|h2s(bf16)  ~66 MB
    char* p = (char*)d_ws;
    int*    deg    = (int*)p;     p += (size_t)n * 4;
    int*    offs   = (int*)p;     p += (size_t)n * 4;
    int*    cursor = (int*)p;     p += (size_t)n * 4;
    int*    bsum   = (int*)p;     p += 1024;
    float*  dis    = (float*)p;   p += (size_t)n * 4;
    int*    adj    = (int*)p;     p += (size_t)e * 4;
    ushort* hs     = (ushort*)p;  p += (size_t)n * DH * 2;
    ushort* h1     = (ushort*)p;  p += (size_t)n * DH * 2;
    ushort* h2s    = (ushort*)p;

    int nb = (n + 1023) / 1024;

    k_init_deg<<<(n + 255) / 256, 256, 0, stream>>>(deg, n);
    k_count<<<(e + 255) / 256, 256, 0, stream>>>(dst, deg, e);
    k_dis<<<(n + 255) / 256, 256, 0, stream>>>(deg, dis, n);
    k_scan1<<<nb, 256, 0, stream>>>(deg, offs, bsum, n);
    k_scan2<<<1, 256, 0, stream>>>(bsum, nb);
    k_scan3<<<(n + 255) / 256, 256, 0, stream>>>(offs, cursor, bsum, n);
    k_fill<<<1024, 256, 0, stream>>>(src, dst, cursor, adj, e, n);

    k_gemm1<<<(n + 127) / 128, 256, 0, stream>>>(x, W1, dis, hs, n);
    k_agg1<<<(n + 3) / 4, 256, 0, stream>>>(hs, dis, offs, deg, adj, b1, h1, n);
    k_gemm2<<<(n * 8 + 255) / 256, 256, 0, stream>>>(h1, W2, dis, h2s, n);
    k_agg2_lsm<<<(n + 7) / 8, 256, 0, stream>>>(h2s, dis, offs, deg, adj, b2, out, n);
}